// Round 7
// baseline (119.102 us; speedup 1.0000x reference)
//
#include <hip/hip_runtime.h>
#include <hip/hip_bf16.h>
#include <math.h>

#define N_ROWS 8192
#define DIM    512            // fp8 row = 512 B
#define GRPB   16384          // 32 rows x 512 B per row-group
#define NBR    64             // row tiles of 128
#define NBC    32             // col tiles of 256
#define NBLK   1056           // triangular-ish blocks: sum_{p<32} 2*(32-p)

typedef float floatx16 __attribute__((ext_vector_type(16)));
typedef long  longx2   __attribute__((ext_vector_type(2)));

// ------------- Kernel 1: L2-normalize fp32 -> fp8 e4m3 (x16), BLOCKED layout
// E8 layout: group g = row/32 (32 rows), pair s2 = k/32:
//   addr(g, s2, lane, cb) = g*16384 + s2*1024 + lane*16 + cb
// where lane = h*32 + (row%32), and the 16-B chunk holds:
//   bytes 0-7  = row, k in [32*s2      + 8h, +8)   (MFMA kstep 2*s2,   half h)
//   bytes 8-15 = row, k in [32*s2 + 16 + 8h, +8)   (MFMA kstep 2*s2+1, half h)
// -> one coalesced 1-KB wave load = one full 32x32x16 fp8 MFMA operand pair.
__global__ __launch_bounds__(128) void normalize_kernel(
    const float* __restrict__ emb, unsigned char* __restrict__ out,
    float* __restrict__ loss_out, int zero_out)
{
    const int row = blockIdx.x;
    const int t   = threadIdx.x;
    if (zero_out && row == 0 && t == 0) loss_out[0] = 0.0f;  // atomic-fallback only

    const float4* rp = (const float4*)(emb + (size_t)row * DIM);
    float4 v = rp[t];
    float ss = v.x*v.x + v.y*v.y + v.z*v.z + v.w*v.w;

    #pragma unroll
    for (int off = 32; off > 0; off >>= 1) ss += __shfl_down(ss, off);

    __shared__ float sred[2];
    if ((t & 63) == 0) sred[t >> 6] = ss;
    __syncthreads();
    const float tot = sred[0] + sred[1];
    const float rs  = 16.0f / fmaxf(sqrtf(tot), 1e-12f);   // normalize * 16

    int pk = 0;
    pk = __builtin_amdgcn_cvt_pk_fp8_f32(v.x * rs, v.y * rs, pk, false);
    pk = __builtin_amdgcn_cvt_pk_fp8_f32(v.z * rs, v.w * rs, pk, true);

    const int k0     = 4 * t;            // 4 bytes, same (s2, parity, h)
    const int g      = row >> 5;
    const int l32    = row & 31;
    const int s2     = k0 >> 5;
    const int w      = k0 & 31;
    const int parity = (w >> 4) & 1;
    const int h      = (w >> 3) & 1;
    const int b      = w & 7;
    *(int*)(out + (size_t)g * GRPB + s2 * 1024 + (h*32 + l32) * 16
                + parity * 8 + b) = pk;
}

// ------------- Kernel 2: LDS-free fp8 E*E^T + contrastive loss ---------------
// Block tile 128 rows x 256 cols; 4 waves 2x2; wave = 64x128 = 2x4 of 32x32.
// All operands via coalesced 1-KB global b128 loads from the blocked layout
// (L1/L2-resident). No LDS, no barriers in the K-loop, no DS-pipe traffic.
// Upper triangle only: per-element mask gj > gi, whole sum x2.
__global__ __launch_bounds__(256) void gemmloss_kernel(
    const unsigned char* __restrict__ E, const int* __restrict__ labels,
    float* __restrict__ partials, float* __restrict__ out, int use_partials)
{
    // ---- decode block id: pairs p = br/2; 2*(32-p) blocks per pair ----
    const int bid = blockIdx.x;
    int p = 0, cum = 0;
    while (cum + 2 * (32 - p) <= bid) { cum += 2 * (32 - p); ++p; }
    const int idx = bid - cum;
    const int np  = 32 - p;
    const int br  = 2 * p + (idx >= np);
    const int bc  = p + (idx >= np ? idx - np : idx);

    const int row0 = br * 128;
    const int col0 = bc * 256;

    const int t    = threadIdx.x;
    const int wave = t >> 6;
    const int lane = t & 63;
    const int wr   = wave >> 1;   // 0..1 : rows wr*64..+63
    const int wc   = wave & 1;    // 0..1 : cols wc*128..+127
    const int l32  = lane & 31;
    const int h    = lane >> 5;

    // fragment base pointers (blocked layout, +s2*1024 per step)
    const unsigned char* pA[2];
    const unsigned char* pB[4];
    #pragma unroll
    for (int mi = 0; mi < 2; ++mi)
        pA[mi] = E + (size_t)(br*4 + wr*2 + mi) * GRPB + lane * 16;
    #pragma unroll
    for (int ni = 0; ni < 4; ++ni)
        pB[ni] = E + (size_t)(bc*8 + wc*4 + ni) * GRPB + lane * 16;

    floatx16 acc[2][4] = {};

    longx2 ca[2], cb[4];
    #pragma unroll
    for (int mi = 0; mi < 2; ++mi) ca[mi] = *(const longx2*)(pA[mi]);
    #pragma unroll
    for (int ni = 0; ni < 4; ++ni) cb[ni] = *(const longx2*)(pB[ni]);

    #pragma unroll 5
    for (int s2 = 0; s2 < 15; ++s2) {
        longx2 na[2], nb[4];
        const int o = (s2 + 1) * 1024;
        #pragma unroll
        for (int mi = 0; mi < 2; ++mi) na[mi] = *(const longx2*)(pA[mi] + o);
        #pragma unroll
        for (int ni = 0; ni < 4; ++ni) nb[ni] = *(const longx2*)(pB[ni] + o);

        #pragma unroll
        for (int mi = 0; mi < 2; ++mi)
            #pragma unroll
            for (int ni = 0; ni < 4; ++ni) {
                acc[mi][ni] = __builtin_amdgcn_mfma_f32_32x32x16_fp8_fp8(
                    ca[mi].x, cb[ni].x, acc[mi][ni], 0, 0, 0);
                acc[mi][ni] = __builtin_amdgcn_mfma_f32_32x32x16_fp8_fp8(
                    ca[mi].y, cb[ni].y, acc[mi][ni], 0, 0, 0);
            }
        #pragma unroll
        for (int mi = 0; mi < 2; ++mi) ca[mi] = na[mi];
        #pragma unroll
        for (int ni = 0; ni < 4; ++ni) cb[ni] = nb[ni];
    }
    #pragma unroll
    for (int mi = 0; mi < 2; ++mi)
        #pragma unroll
        for (int ni = 0; ni < 4; ++ni) {
            acc[mi][ni] = __builtin_amdgcn_mfma_f32_32x32x16_fp8_fp8(
                ca[mi].x, cb[ni].x, acc[mi][ni], 0, 0, 0);
            acc[mi][ni] = __builtin_amdgcn_mfma_f32_32x32x16_fp8_fp8(
                ca[mi].y, cb[ni].y, acc[mi][ni], 0, 0, 0);
        }

    // ---- epilogue: loss, upper triangle (gj > gi) only ----
    // 32x32 C/D layout: col = lane&31, row = (reg&3)+8*(reg>>2)+4*(lane>>5)
    float lsum = 0.0f;
    #pragma unroll
    for (int mi = 0; mi < 2; ++mi) {
        int rl[16], ri[16];
        #pragma unroll
        for (int reg = 0; reg < 16; ++reg) {
            ri[reg] = row0 + wr*64 + mi*32 + (reg & 3) + 8*(reg >> 2) + 4*h;
            rl[reg] = labels[ri[reg]];
        }
        #pragma unroll
        for (int ni = 0; ni < 4; ++ni) {
            const int gj = col0 + wc*128 + ni*32 + l32;
            const int cl = labels[gj];
            #pragma unroll
            for (int reg = 0; reg < 16; ++reg) {
                if (gj > ri[reg]) {
                    const float s = acc[mi][ni][reg] * (1.0f / 256.0f);
                    if (rl[reg] == cl) {
                        const float u = 1.0f - s;
                        lsum += u * u;
                    } else {
                        const float u = s - 0.5f;
                        if (u > 0.0f) lsum += u * u;
                    }
                }
            }
        }
    }

    #pragma unroll
    for (int off = 32; off > 0; off >>= 1) lsum += __shfl_down(lsum, off);

    __shared__ float red[4];
    if (lane == 0) red[wave] = lsum;
    __syncthreads();
    if (t == 0) {
        const float tot = red[0] + red[1] + red[2] + red[3];
        if (use_partials) partials[bid] = tot;                         // raw upper-tri sum
        else atomicAdd(out, tot * (2.0f / 67100672.0f));               // fallback
    }
}

// ------------- Kernel 3: sum partials -> d_out (x2 for symmetry) -------------
__global__ __launch_bounds__(256) void reduce_kernel(
    const float* __restrict__ partials, float* __restrict__ out)
{
    const int t = threadIdx.x;
    float s = 0.0f;
    for (int i = t; i < NBLK; i += 256) s += partials[i];
    #pragma unroll
    for (int off = 32; off > 0; off >>= 1) s += __shfl_down(s, off);
    __shared__ float r[4];
    if ((t & 63) == 0) r[t >> 6] = s;
    __syncthreads();
    if (t == 0)
        out[0] = (r[0] + r[1] + r[2] + r[3]) * (2.0f / 67100672.0f); // 2/(N*(N-1))
}

// ---------------- launch ----------------
extern "C" void kernel_launch(void* const* d_in, const int* in_sizes, int n_in,
                              void* d_out, int out_size, void* d_ws, size_t ws_size,
                              hipStream_t stream)
{
    (void)in_sizes; (void)n_in; (void)out_size;

    const float* emb    = (const float*)d_in[0];
    const int*   labels = (const int*)d_in[1];
    float*       out    = (float*)d_out;
    unsigned char* E8   = (unsigned char*)d_ws;   // 4 MB fp8, blocked layout

    const size_t e8_bytes = (size_t)N_ROWS * DIM;
    const int use_partials = (ws_size >= e8_bytes + NBLK * sizeof(float)) ? 1 : 0;
    float* partials = (float*)((unsigned char*)d_ws + e8_bytes);

    normalize_kernel<<<N_ROWS, 128, 0, stream>>>(emb, E8, out, !use_partials);
    gemmloss_kernel<<<NBLK, 256, 0, stream>>>(E8, labels, partials, out, use_partials);
    if (use_partials)
        reduce_kernel<<<1, 256, 0, stream>>>(partials, out);
}